// Round 1
// baseline (260.467 us; speedup 1.0000x reference)
//
#include <hip/hip_runtime.h>

#define NP 2000   // points
#define PP 2048   // padded points
#define NB 128    // N*t
#define NC 64     // channels

// window caps (span guaranteed for |grid|<=0.05; fallback path covers the rest)
#define C0 8
#define C1 6
#define C2 4
#define C3 4
#define Q0 0
#define Q1 64
#define Q2 100
#define Q3 116
#define SLABQ 132          // total window pixels per (b,ch)
#define NBUCK 65           // C0*C0 + 1 overflow

#define K2_EXTRA 514       // featP/biasP copy blocks: 514*256*4 = 257*2048 exactly

typedef float f32x2 __attribute__((ext_vector_type(2)));

// ---- ws layout ----
#define WIN_OFF   0u                         // int wino[8]
#define PERM_OFF  4096u                      // int perm[PP]
#define X0_OFF    (PERM_OFF + PP*4u)         // int  x0a[4][PP]
#define Y0_OFF    (X0_OFF + 4u*PP*4u)
#define WX_OFF    (Y0_OFF + 4u*PP*4u)
#define WY_OFF    (WX_OFF + 4u*PP*4u)
#define BIASP_OFF (WY_OFF + 4u*PP*4u)        // float biasP[PP]
#define OFFA_OFF  (BIASP_OFF + PP*4u)        // int offa[4][PP]: comp4 offset or -1
#define FEATP_OFF 262144u                    // float featP[256][PP] = 2 MB
#define COMP4_OFF (FEATP_OFF + 256u*PP*4u)   // float4 comp4[NB][NC][SLABQ] = 17.3 MB

// ---------------- K1: params + bbox + counting sort by level-0 pixel ----------------
__global__ __launch_bounds__(256) void k1_params(const float* __restrict__ grid,
    int* __restrict__ wino, int* __restrict__ perm,
    int* __restrict__ x0a, int* __restrict__ y0a,
    float* __restrict__ wxa, float* __restrict__ wya,
    int* __restrict__ offa) {
  __shared__ int smnx[4], smny[4];
  __shared__ int so[8];
  __shared__ int cnt[NBUCK], offs[NBUCK];
  int t = threadIdx.x;
  if (t < 4) { smnx[t] = 1000; smny[t] = 1000; }
  if (t < NBUCK) cnt[t] = 0;
  __syncthreads();
  int mnx[4] = {1000,1000,1000,1000}, mny[4] = {1000,1000,1000,1000};
  for (int p = t; p < NP; p += 256) {
    float gx = fminf(1.f, fmaxf(-1.f, grid[2*p]));
    float gy = fminf(1.f, fmaxf(-1.f, grid[2*p+1]));
    #pragma unroll
    for (int l = 0; l < 4; l++) {
      int W = 64 >> l;
      float ix = (gx + 1.f) * 0.5f * (float)(W - 1);
      float iy = (gy + 1.f) * 0.5f * (float)(W - 1);
      int x0 = min(max((int)floorf(ix), 0), W - 2);
      int y0 = min(max((int)floorf(iy), 0), W - 2);
      mnx[l] = min(mnx[l], x0); mny[l] = min(mny[l], y0);
    }
  }
  #pragma unroll
  for (int l = 0; l < 4; l++) { atomicMin(&smnx[l], mnx[l]); atomicMin(&smny[l], mny[l]); }
  __syncthreads();
  if (t < 4) {
    int l = t, W = 64 >> l;
    int cap = (l == 0) ? C0 : (l == 1) ? C1 : (l == 2) ? C2 : C3;
    int ox = min(max(smnx[l], 0), W - cap);
    int oy = min(max(smny[l], 0), W - cap);
    so[l] = ox; so[4+l] = oy; wino[l] = ox; wino[4+l] = oy;
  }
  __syncthreads();
  // histogram over level-0 buckets
  for (int p = t; p < NP; p += 256) {
    float gx = fminf(1.f, fmaxf(-1.f, grid[2*p]));
    float gy = fminf(1.f, fmaxf(-1.f, grid[2*p+1]));
    float ix = (gx + 1.f) * 0.5f * 63.f, iy = (gy + 1.f) * 0.5f * 63.f;
    int x0 = min(max((int)floorf(ix), 0), 62), y0 = min(max((int)floorf(iy), 0), 62);
    int lx = x0 - so[0], ly = y0 - so[4];
    int bkt = (lx >= 0 && ly >= 0 && lx <= C0-2 && ly <= C0-2) ? ly*C0 + lx : NBUCK-1;
    atomicAdd(&cnt[bkt], 1);
  }
  __syncthreads();
  if (t == 0) { int s = 0; for (int i = 0; i < NBUCK; i++) { offs[i] = s; s += cnt[i]; } }
  __syncthreads();
  // placement + permuted param writes (incl. precomputed comp4 offsets)
  for (int p = t; p < NP; p += 256) {
    float gx = fminf(1.f, fmaxf(-1.f, grid[2*p]));
    float gy = fminf(1.f, fmaxf(-1.f, grid[2*p+1]));
    float ix = (gx + 1.f) * 0.5f * 63.f, iy = (gy + 1.f) * 0.5f * 63.f;
    int x0 = min(max((int)floorf(ix), 0), 62), y0 = min(max((int)floorf(iy), 0), 62);
    int lx0 = x0 - so[0], ly0 = y0 - so[4];
    int bkt = (lx0 >= 0 && ly0 >= 0 && lx0 <= C0-2 && ly0 <= C0-2) ? ly0*C0 + lx0 : NBUCK-1;
    int slot = atomicAdd(&offs[bkt], 1);
    perm[slot] = p;
    #pragma unroll
    for (int l = 0; l < 4; l++) {
      int W = 64 >> l;
      float ix2 = (gx + 1.f) * 0.5f * (float)(W - 1);
      float iy2 = (gy + 1.f) * 0.5f * (float)(W - 1);
      int xx = min(max((int)floorf(ix2), 0), W - 2);
      int yy = min(max((int)floorf(iy2), 0), W - 2);
      // ref's clamped case (ix==W-1): wx becomes 1, weight shifts to xx+1 -> identical
      x0a[l*PP+slot] = xx; y0a[l*PP+slot] = yy;
      wxa[l*PP+slot] = ix2 - (float)xx; wya[l*PP+slot] = iy2 - (float)yy;
      int C = (l == 0) ? C0 : (l == 1) ? C1 : (l == 2) ? C2 : C3;
      int Q = (l == 0) ? Q0 : (l == 1) ? Q1 : (l == 2) ? Q2 : Q3;
      int lx = xx - so[l], ly = yy - so[4+l];
      offa[l*PP+slot] =
          (lx >= 0 && ly >= 0 && lx <= C-2 && ly <= C-2) ? (Q + ly*C + lx) : -1;
    }
  }
}

// ---------------- K2: pooled windows -> corner-packed comp4 [b][ch][q]; featP/biasP ----
__global__ __launch_bounds__(256) void k2_pool(const float* __restrict__ x,
    const int* __restrict__ wino, const int* __restrict__ perm,
    const float* __restrict__ feat, const float* __restrict__ bias,
    float4* __restrict__ comp4, float* __restrict__ featP, float* __restrict__ biasP) {
  int t = threadIdx.x;
  int bx = blockIdx.x;
  if (bx >= NB*NC) {
    int idx = (bx - NB*NC) * 256 + t;           // [0, 131584)
    #pragma unroll
    for (int j = 0; j < 4; j++) {
      int e = idx + j * (K2_EXTRA * 256);       // [0, 526336) exactly
      int r = e >> 11, i = e & 2047;
      int pm = (i < NP) ? perm[i] : 0;
      if (r < 256) featP[(r << 11) + i] = (i < NP) ? feat[r*NP + pm] : 0.f;
      else         biasP[i]            = (i < NP) ? bias[pm] : 0.f;
    }
    return;
  }
  __shared__ float win[SLABQ];
  __shared__ float part3[64];
  __shared__ int so[8];
  if (t < 8) so[t] = wino[t];
  __syncthreads();
  int b = bx >> 6, ch = bx & 63;
  int n = b >> 4, tt = b & 15;
  const float* xp = x + ((size_t)(((n*NC + ch) << 4) | tt) << 12);
  if (t < 64) {               // l0: 8x8 copy
    int r = t >> 3, c = t & 7;
    win[Q0 + t] = xp[(so[4]+r)*64 + so[0]+c];
  } else if (t < 100) {       // l1: 6x6, mean of 2x2
    int i = t - 64; int r = i / 6, c = i - r*6;
    const float* s = xp + ((so[5]+r)*2)*64 + (so[1]+c)*2;
    win[Q1 + i] = (s[0] + s[1] + s[64] + s[65]) * 0.25f;
  } else if (t < 116) {       // l2: 4x4, mean of 4x4
    int i = t - 100; int r = i >> 2, c = i & 3;
    const float* s = xp + ((so[6]+r)*4)*64 + (so[2]+c)*4;
    float v = 0.f;
    #pragma unroll
    for (int rr = 0; rr < 4; rr++)
      #pragma unroll
      for (int cc = 0; cc < 4; cc++) v += s[rr*64 + cc];
    win[Q2 + i] = v * (1.f/16.f);
  } else if (t < 180) {       // l3: 4x4, mean of 8x8 -- 4 partials per px (2 rows each)
    int i = t - 116; int px = i >> 2, part = i & 3;
    int r = px >> 2, c = px & 3;
    const float* s = xp + ((so[7]+r)*8 + part*2)*64 + (so[3]+c)*8;
    float v = 0.f;
    #pragma unroll
    for (int rr = 0; rr < 2; rr++)
      #pragma unroll
      for (int cc = 0; cc < 8; cc++) v += s[rr*64 + cc];
    part3[i] = v;
  }
  __syncthreads();
  if (t < 16) win[Q3 + t] = (part3[4*t] + part3[4*t+1] + part3[4*t+2] + part3[4*t+3]) * (1.f/64.f);
  __syncthreads();
  if (t < SLABQ) {
    int q = t, base, C, loc, ly, lx;
    if (q < Q1)      { base = Q0; C = C0; loc = q - base; ly = loc >> 3; lx = loc & 7; }
    else if (q < Q2) { base = Q1; C = C1; loc = q - base; ly = loc / 6; lx = loc - ly*6; }
    else if (q < Q3) { base = Q2; C = C2; loc = q - base; ly = loc >> 2; lx = loc & 3; }
    else             { base = Q3; C = C3; loc = q - base; ly = loc >> 2; lx = loc & 3; }
    int lx1 = min(lx + 1, C - 1), ly1 = min(ly + 1, C - 1);
    float4 v;
    v.x = win[base + ly*C  + lx];
    v.y = win[base + ly*C  + lx1];
    v.z = win[base + ly1*C + lx];
    v.w = win[base + ly1*C + lx1];
    // [b][ch][q] layout: block writes a contiguous 2112B burst (coalesced)
    comp4[(size_t)(b*NC + ch)*SLABQ + q] = v;
  }
}

// ---------------- K3 helpers ----------------
// cbq = comp4 + b*NC*SLABQ + q; k-stride = SLABQ float4s. Packed f32x2 accumulation.
__device__ __forceinline__ float level_sum(const float4* __restrict__ cbq,
                                           const float* __restrict__ fp,
                                           float wx, float wy) {
  float w11 = wx*wy, w01 = wx - w11, w10 = wy - w11, w00 = 1.f - wx - wy + w11;
  f32x2 A0 = {0.f, 0.f}, A1 = {0.f, 0.f};
  #pragma unroll 8
  for (int k = 0; k < NC; k++) {
    float4 v = cbq[(size_t)k * SLABQ];
    float f = fp[k << 11];          // featP stride PP=2048
    f32x2 vf = {f, f};
    f32x2 v01 = {v.x, v.y}, v23 = {v.z, v.w};
    A0 += vf * v01;                 // v_pk_fma_f32 candidates
    A1 += vf * v23;
  }
  return w00*A0.x + w01*A0.y + w10*A1.x + w11*A1.y;
}

// slow fallback: pool on the fly straight from x (never hit for bench data)
__device__ __noinline__ float level_sum_slow(const float* __restrict__ xpl0, int S,
                                             int x0, int y0,
                                             const float* __restrict__ fp,
                                             float wx, float wy) {
  float w11 = wx*wy, w01 = wx - w11, w10 = wy - w11, w00 = 1.f - wx - wy + w11;
  float A00 = 0.f, A01 = 0.f, A10 = 0.f, A11 = 0.f;
  float inv = 1.f / (float)(S * S);
  for (int k = 0; k < NC; k++) {
    const float* pl = xpl0 + (size_t)k * 65536;
    float v00 = 0.f, v01 = 0.f, v10 = 0.f, v11 = 0.f;
    for (int rr = 0; rr < S; rr++)
      for (int cc = 0; cc < S; cc++) {
        v00 += pl[(y0*S + rr)*64 + x0*S + cc];
        v01 += pl[(y0*S + rr)*64 + (x0+1)*S + cc];
        v10 += pl[((y0+1)*S + rr)*64 + x0*S + cc];
        v11 += pl[((y0+1)*S + rr)*64 + (x0+1)*S + cc];
      }
    float f = fp[0];
    A00 += f*v00*inv; A01 += f*v01*inv; A10 += f*v10*inv; A11 += f*v11*inv;
    fp += PP;
  }
  return w00*A00 + w01*A01 + w10*A10 + w11*A11;
}

// ---------------- K3: main contraction (sorted index space) ----------------
__global__ __launch_bounds__(256) void k3_main(const float* __restrict__ x,
    const float* __restrict__ featP, const float* __restrict__ biasP,
    const float4* __restrict__ comp4,
    const int* __restrict__ perm,
    const int* __restrict__ x0a, const int* __restrict__ y0a,
    const float* __restrict__ wxa, const float* __restrict__ wya,
    const int* __restrict__ offa,
    float* __restrict__ out) {
  int bx = blockIdx.x;                 // 0..1023
  int xcd = bx & 7, j = bx >> 3;       // all 8 p-tiles of a b on one XCD
  int b = (xcd << 4) | (j & 15);
  int pt = j >> 4;
  int i = pt * 256 + threadIdx.x;
  if (i >= NP) return;
  const float4* cb = comp4 + (size_t)b * NC * SLABQ;
  int o0 = offa[i], o1 = offa[PP+i], o2 = offa[2*PP+i], o3 = offa[3*PP+i];
  float wx0 = wxa[i],      wy0 = wya[i];
  float wx1 = wxa[PP+i],   wy1 = wya[PP+i];
  float wx2 = wxa[2*PP+i], wy2 = wya[2*PP+i];
  float wx3 = wxa[3*PP+i], wy3 = wya[3*PP+i];
  float acc;
  if ((o0 | o1 | o2 | o3) >= 0) {
    // hot path: all 4 levels in-window -> fused k-loop, 4 comp4 streams +
    // 4 featP streams in flight (4x the MLP of the per-level version)
    const float4* cq0 = cb + o0;
    const float4* cq1 = cb + o1;
    const float4* cq2 = cb + o2;
    const float4* cq3 = cb + o3;
    const float* f0 = featP + i;
    const float* f1 = f0 + (1 << 17);
    const float* f2 = f0 + (2 << 17);
    const float* f3 = f0 + (3 << 17);
    f32x2 A00 = {0.f,0.f}, A01 = {0.f,0.f};
    f32x2 A10 = {0.f,0.f}, A11 = {0.f,0.f};
    f32x2 A20 = {0.f,0.f}, A21 = {0.f,0.f};
    f32x2 A30 = {0.f,0.f}, A31 = {0.f,0.f};
    #pragma unroll 2
    for (int k = 0; k < NC; k++) {
      float4 v0 = cq0[(size_t)k * SLABQ];
      float4 v1 = cq1[(size_t)k * SLABQ];
      float4 v2 = cq2[(size_t)k * SLABQ];
      float4 v3 = cq3[(size_t)k * SLABQ];
      float g0 = f0[k << 11], g1 = f1[k << 11], g2 = f2[k << 11], g3 = f3[k << 11];
      f32x2 G0 = {g0, g0}, G1 = {g1, g1}, G2 = {g2, g2}, G3 = {g3, g3};
      A00 += G0 * (f32x2){v0.x, v0.y};  A01 += G0 * (f32x2){v0.z, v0.w};
      A10 += G1 * (f32x2){v1.x, v1.y};  A11 += G1 * (f32x2){v1.z, v1.w};
      A20 += G2 * (f32x2){v2.x, v2.y};  A21 += G2 * (f32x2){v2.z, v2.w};
      A30 += G3 * (f32x2){v3.x, v3.y};  A31 += G3 * (f32x2){v3.z, v3.w};
    }
    float w11, w01, w10, w00;
    w11 = wx0*wy0; w01 = wx0 - w11; w10 = wy0 - w11; w00 = 1.f - wx0 - wy0 + w11;
    acc  = w00*A00.x + w01*A00.y + w10*A01.x + w11*A01.y;
    w11 = wx1*wy1; w01 = wx1 - w11; w10 = wy1 - w11; w00 = 1.f - wx1 - wy1 + w11;
    acc += w00*A10.x + w01*A10.y + w10*A11.x + w11*A11.y;
    w11 = wx2*wy2; w01 = wx2 - w11; w10 = wy2 - w11; w00 = 1.f - wx2 - wy2 + w11;
    acc += w00*A20.x + w01*A20.y + w10*A21.x + w11*A21.y;
    w11 = wx3*wy3; w01 = wx3 - w11; w10 = wy3 - w11; w00 = 1.f - wx3 - wy3 + w11;
    acc += w00*A30.x + w01*A30.y + w10*A31.x + w11*A31.y;
  } else {
    // cold path: at least one level out-of-window (never hit for bench data)
    int n = b >> 4, tt = b & 15;
    const float* xpl0 = x + ((size_t)((n << 10) | tt) << 12);
    acc = 0.f;
    { // level 0
      if (o0 >= 0)
        acc += level_sum(cb + o0, featP + i, wx0, wy0);
      else {
        int x0 = x0a[i], y0 = y0a[i];
        float w11 = wx0*wy0, w01 = wx0 - w11, w10 = wy0 - w11, w00 = 1.f - wx0 - wy0 + w11;
        float A00 = 0.f, A01 = 0.f, A10 = 0.f, A11 = 0.f;
        const float* Lp = xpl0 + y0*64 + x0;
        const float* fp = featP + i;
        for (int k = 0; k < NC; k++) {
          float f = fp[0];
          A00 += f*Lp[0]; A01 += f*Lp[1]; A10 += f*Lp[64]; A11 += f*Lp[65];
          Lp += 65536; fp += PP;
        }
        acc += w00*A00 + w01*A01 + w10*A10 + w11*A11;
      }
    }
    if (o1 >= 0) acc += level_sum(cb + o1, featP + (1 << 17) + i, wx1, wy1);
    else         acc += level_sum_slow(xpl0, 2, x0a[PP+i],   y0a[PP+i],
                                       featP + (1 << 17) + i, wx1, wy1);
    if (o2 >= 0) acc += level_sum(cb + o2, featP + (2 << 17) + i, wx2, wy2);
    else         acc += level_sum_slow(xpl0, 4, x0a[2*PP+i], y0a[2*PP+i],
                                       featP + (2 << 17) + i, wx2, wy2);
    if (o3 >= 0) acc += level_sum(cb + o3, featP + (3 << 17) + i, wx3, wy3);
    else         acc += level_sum_slow(xpl0, 8, x0a[3*PP+i], y0a[3*PP+i],
                                       featP + (3 << 17) + i, wx3, wy3);
  }
  out[b*NP + perm[i]] = acc + biasP[i];
}

extern "C" void kernel_launch(void* const* d_in, const int* in_sizes, int n_in,
                              void* d_out, int out_size, void* d_ws, size_t ws_size,
                              hipStream_t stream) {
  (void)in_sizes; (void)n_in; (void)out_size; (void)ws_size;
  const float* x    = (const float*)d_in[0];
  const float* grid = (const float*)d_in[1];
  const float* feat = (const float*)d_in[2];
  const float* bias = (const float*)d_in[3];
  float* out = (float*)d_out;
  char* ws = (char*)d_ws;
  int*    wino  = (int*)(ws + WIN_OFF);
  int*    perm  = (int*)(ws + PERM_OFF);
  int*    x0a   = (int*)(ws + X0_OFF);
  int*    y0a   = (int*)(ws + Y0_OFF);
  float*  wxa   = (float*)(ws + WX_OFF);
  float*  wya   = (float*)(ws + WY_OFF);
  float*  biasP = (float*)(ws + BIASP_OFF);
  int*    offa  = (int*)(ws + OFFA_OFF);
  float*  featP = (float*)(ws + FEATP_OFF);
  float4* comp4 = (float4*)(ws + COMP4_OFF);

  k1_params<<<1, 256, 0, stream>>>(grid, wino, perm, x0a, y0a, wxa, wya, offa);
  k2_pool<<<dim3(NB*NC + K2_EXTRA), 256, 0, stream>>>(x, wino, perm, feat, bias,
                                                      comp4, featP, biasP);
  k3_main<<<dim3(1024), 256, 0, stream>>>(x, featP, biasP, comp4, perm,
                                          x0a, y0a, wxa, wya, offa, out);
}